// Round 1
// baseline (6875.676 us; speedup 1.0000x reference)
//
#include <hip/hip_runtime.h>
#include <math.h>

#define B_ 4
#define H_ 8
#define L_ 1520
#define DM_ 512
#define DFF_ 2048
#define DH_ 64
#define SK_ 40
#define ML_ (B_*L_)   /* 6080 rows */

// ---------------- positional encoding (double precision to match numpy) ----
__global__ __launch_bounds__(256) void pe_kernel(float* __restrict__ pe) {
  int idx = blockIdx.x * 256 + threadIdx.x;
  if (idx >= L_ * DM_) return;
  int pos = idx / DM_, i = idx % DM_;
  double expo = (double)(2 * (i / 2)) / (double)DM_;
  double ang = (double)pos / pow(10000.0, expo);
  pe[idx] = (i & 1) ? (float)cos(ang) : (float)sin(ang);
}

// ---------------- x = inflow[:,2:14].reshape(B,-1,12) (contiguous slice) ---
__global__ __launch_bounds__(256) void extract_x(const float* __restrict__ inflow,
                                                 float* __restrict__ X) {
  int idx = blockIdx.x * 256 + threadIdx.x;
  if (idx >= ML_ * 12) return;
  int b = idx / (L_ * 12);
  int rem = idx - b * (L_ * 12);
  X[idx] = inflow[(size_t)b * 14 * L_ + 2 * L_ + rem];
}

// ---------------- generic fp32 GEMM: C = act(A@B + bias + res) -------------
// A[M,K], B[K,N] row-major. res indexed res[(m % res_mod)*N + n] (PE reuse).
// act: 0 none, 1 gelu(tanh), 2 relu
__device__ __forceinline__ float gelu_tanh(float x) {
  float x3 = x * x * x;
  return 0.5f * x * (1.f + tanhf(0.79788456080286536f * (x + 0.044715f * x3)));
}

__global__ __launch_bounds__(256) void gemm_f32(
    const float* __restrict__ A, const float* __restrict__ Bm,
    const float* __restrict__ bias, const float* __restrict__ res,
    float* __restrict__ C, int M, int N, int K, int res_mod, int act) {
  __shared__ float As[16][65];
  __shared__ float Bs[16][64];
  int bm = blockIdx.y * 64, bn = blockIdx.x * 64;
  int tid = threadIdx.x;
  int tx = tid % 16, ty = tid / 16;
  float acc[4][4] = {};
  for (int k0 = 0; k0 < K; k0 += 16) {
#pragma unroll
    for (int i = 0; i < 4; ++i) {
      int idx = tid + i * 256;
      int r = idx / 16, c = idx % 16;
      int gm = bm + r, gk = k0 + c;
      As[c][r] = (gm < M && gk < K) ? A[(size_t)gm * K + gk] : 0.f;
    }
#pragma unroll
    for (int i = 0; i < 4; ++i) {
      int idx = tid + i * 256;
      int r = idx / 64, c = idx % 64;
      int gk = k0 + r, gn = bn + c;
      Bs[r][c] = (gk < K && gn < N) ? Bm[(size_t)gk * N + gn] : 0.f;
    }
    __syncthreads();
#pragma unroll
    for (int kk = 0; kk < 16; ++kk) {
      float a[4], b[4];
#pragma unroll
      for (int i = 0; i < 4; ++i) a[i] = As[kk][ty + 16 * i];
#pragma unroll
      for (int j = 0; j < 4; ++j) b[j] = Bs[kk][tx + 16 * j];
#pragma unroll
      for (int i = 0; i < 4; ++i)
#pragma unroll
        for (int j = 0; j < 4; ++j) acc[i][j] += a[i] * b[j];
    }
    __syncthreads();
  }
#pragma unroll
  for (int i = 0; i < 4; ++i) {
    int gm = bm + ty + 16 * i;
    if (gm >= M) continue;
#pragma unroll
    for (int j = 0; j < 4; ++j) {
      int gn = bn + tx + 16 * j;
      if (gn >= N) continue;
      float v = acc[i][j];
      if (bias) v += bias[gn];
      if (res) v += res[(size_t)(gm % res_mod) * N + gn];
      if (act == 1) v = gelu_tanh(v);
      else if (act == 2) v = fmaxf(v, 0.f);
      C[(size_t)gm * N + gn] = v;
    }
  }
}

// ---------------- layernorm (in-place, width 512) ---------------------------
__global__ __launch_bounds__(256) void layernorm_ip(float* __restrict__ Xb,
                                                    const float* __restrict__ g,
                                                    const float* __restrict__ bta) {
  int row = blockIdx.x;
  float* x = Xb + (size_t)row * DM_;
  int tid = threadIdx.x;
  float v0 = x[tid], v1 = x[tid + 256];
  __shared__ float red[256];
  red[tid] = v0 + v1;
  __syncthreads();
  for (int s = 128; s; s >>= 1) { if (tid < s) red[tid] += red[tid + s]; __syncthreads(); }
  float mu = red[0] / (float)DM_;
  __syncthreads();
  float d0 = v0 - mu, d1 = v1 - mu;
  red[tid] = d0 * d0 + d1 * d1;
  __syncthreads();
  for (int s = 128; s; s >>= 1) { if (tid < s) red[tid] += red[tid + s]; __syncthreads(); }
  float rs = rsqrtf(red[0] / (float)DM_ + 1e-5f);
  x[tid] = d0 * rs * g[tid] + bta[tid];
  x[tid + 256] = d1 * rs * g[tid + 256] + bta[tid + 256];
}

// ---------------- ProbSparse: sparsity measure M ----------------------------
// qkv[B*L,1536]: Q at col h*64, K at 512+h*64, V at 1024+h*64
__global__ __launch_bounds__(256) void probM(const float* __restrict__ qkv,
                                             const int* __restrict__ sidx,
                                             float* __restrict__ Mout) {
  int wid = threadIdx.x / 64, lane = threadIdx.x % 64;
  int g = blockIdx.x * 4 + wid;            // g = (b*H + h)*L + l, grid exact
  int l = g % L_;
  int bh = g / L_;
  int h = bh % H_, b = bh / H_;
  __shared__ float qs[4][64];
  qs[wid][lane] = qkv[((size_t)b * L_ + l) * 1536 + h * 64 + lane];
  __syncthreads();
  float dot = 0.f;
  if (lane < SK_) {
    int ks = sidx[l * SK_ + lane];
    const float* krow = qkv + ((size_t)b * L_ + ks) * 1536 + 512 + h * 64;
#pragma unroll
    for (int d = 0; d < 64; ++d) dot += qs[wid][d] * krow[d];
  }
  float vmax = (lane < SK_) ? dot : -INFINITY;
  float vsum = (lane < SK_) ? dot : 0.f;
  for (int off = 32; off; off >>= 1) {
    vmax = fmaxf(vmax, __shfl_xor(vmax, off));
    vsum += __shfl_xor(vsum, off);
  }
  if (lane == 0) Mout[g] = vmax - vsum / (float)L_;
}

// ---------------- top-40 per (b,h), tie-break = smaller index ---------------
__global__ __launch_bounds__(256) void topk40(const float* __restrict__ Mv,
                                              int* __restrict__ top) {
  int bh = blockIdx.x;
  __shared__ float vals[L_];
  __shared__ float rbv[256];
  __shared__ int rbi[256];
  const float* m = Mv + (size_t)bh * L_;
  for (int i = threadIdx.x; i < L_; i += 256) vals[i] = m[i];
  __syncthreads();
  for (int it = 0; it < SK_; ++it) {
    float bv = -INFINITY;
    int bi = -1;
    for (int i = threadIdx.x; i < L_; i += 256) {
      float v = vals[i];
      if (v > bv || (v == bv && (unsigned)i < (unsigned)bi)) { bv = v; bi = i; }
    }
    rbv[threadIdx.x] = bv; rbi[threadIdx.x] = bi;
    __syncthreads();
    for (int s = 128; s; s >>= 1) {
      if (threadIdx.x < s) {
        float ov = rbv[threadIdx.x + s]; int oi = rbi[threadIdx.x + s];
        if (ov > rbv[threadIdx.x] ||
            (ov == rbv[threadIdx.x] && (unsigned)oi < (unsigned)rbi[threadIdx.x])) {
          rbv[threadIdx.x] = ov; rbi[threadIdx.x] = oi;
        }
      }
      __syncthreads();
    }
    if (threadIdx.x == 0) { top[bh * SK_ + it] = rbi[0]; vals[rbi[0]] = -INFINITY; }
    __syncthreads();
  }
}

// ---------------- softmax attention for the 40 selected queries -------------
__global__ __launch_bounds__(256) void prob_ctx_top(const float* __restrict__ qkv,
                                                    const int* __restrict__ top,
                                                    float* __restrict__ ctt) {
  int u = blockIdx.x % SK_;
  int bh = blockIdx.x / SK_;
  int h = bh % H_, b = bh / H_;
  int tid = threadIdx.x;
  __shared__ float q[64];
  __shared__ float sc[L_];
  __shared__ float red[256];
  __shared__ float pv[4][64];
  int ql = top[bh * SK_ + u];
  if (tid < 64) q[tid] = qkv[((size_t)b * L_ + ql) * 1536 + h * 64 + tid];
  __syncthreads();
  for (int k = tid; k < L_; k += 256) {
    const float* krow = qkv + ((size_t)b * L_ + k) * 1536 + 512 + h * 64;
    float dot = 0.f;
#pragma unroll
    for (int d = 0; d < 64; ++d) dot += q[d] * krow[d];
    sc[k] = dot * 0.125f;
  }
  __syncthreads();
  float lm = -INFINITY;
  for (int k = tid; k < L_; k += 256) lm = fmaxf(lm, sc[k]);
  red[tid] = lm; __syncthreads();
  for (int s = 128; s; s >>= 1) { if (tid < s) red[tid] = fmaxf(red[tid], red[tid + s]); __syncthreads(); }
  float mx = red[0];
  __syncthreads();
  float ls = 0.f;
  for (int k = tid; k < L_; k += 256) { float e = expf(sc[k] - mx); sc[k] = e; ls += e; }
  red[tid] = ls; __syncthreads();
  for (int s = 128; s; s >>= 1) { if (tid < s) red[tid] += red[tid + s]; __syncthreads(); }
  float inv = 1.f / red[0];
  int lane = tid % 64, grp = tid / 64;
  float acc = 0.f;
  for (int k = grp; k < L_; k += 4)
    acc += sc[k] * qkv[((size_t)b * L_ + k) * 1536 + 1024 + h * 64 + lane];
  pv[grp][lane] = acc;
  __syncthreads();
  if (tid < 64) {
    float v = (pv[0][tid] + pv[1][tid] + pv[2][tid] + pv[3][tid]) * inv;
    ctt[((size_t)bh * SK_ + u) * 64 + tid] = v;
  }
}

// ---------------- V mean over L per (b,h) -----------------------------------
__global__ __launch_bounds__(256) void vmean_k(const float* __restrict__ qkv,
                                               float* __restrict__ vmean) {
  int bh = blockIdx.x;
  int h = bh % H_, b = bh / H_;
  int lane = threadIdx.x % 64, grp = threadIdx.x / 64;
  __shared__ float pv[4][64];
  float acc = 0.f;
  for (int k = grp; k < L_; k += 4)
    acc += qkv[((size_t)b * L_ + k) * 1536 + 1024 + h * 64 + lane];
  pv[grp][lane] = acc;
  __syncthreads();
  if (threadIdx.x < 64)
    vmean[bh * 64 + threadIdx.x] =
        (pv[0][threadIdx.x] + pv[1][threadIdx.x] + pv[2][threadIdx.x] + pv[3][threadIdx.x]) / (float)L_;
}

// ---------------- ctx = broadcast vmean, then scatter top contexts ----------
__global__ __launch_bounds__(256) void fill_ctx(const float* __restrict__ vmean,
                                                float* __restrict__ ctx) {
  int idx = blockIdx.x * 256 + threadIdx.x;   // grid exact: ML_*DM_/256
  int d = idx % 64;
  int h = (idx / 64) % H_;
  int b = idx / (L_ * DM_);
  ctx[idx] = vmean[(b * H_ + h) * 64 + d];
}

__global__ __launch_bounds__(256) void scatter_ctx(const float* __restrict__ ctt,
                                                   const int* __restrict__ top,
                                                   float* __restrict__ ctx) {
  int idx = blockIdx.x * 256 + threadIdx.x;   // grid exact: B*H*40*64/256
  int d = idx % 64;
  int u = (idx / 64) % SK_;
  int bh = idx / (64 * SK_);
  int h = bh % H_, b = bh / H_;
  int l = top[bh * SK_ + u];
  ctx[((size_t)b * L_ + l) * DM_ + h * 64 + d] = ctt[idx];
}

// ---------------- full cross attention (8 queries per block) ----------------
__global__ __launch_bounds__(256) void cross_attn(const float* __restrict__ qc,
                                                  const float* __restrict__ kvc,
                                                  float* __restrict__ ctx) {
  int qt = blockIdx.x % (L_ / 8);
  int bh = blockIdx.x / (L_ / 8);
  int h = bh % H_, b = bh / H_;
  int q0 = qt * 8;
  int tid = threadIdx.x;
  __shared__ float q[8][64];
  __shared__ float sc[8][L_];
  __shared__ float invs[8];
  __shared__ float pv[4][8][64];
  if (tid < 64) {
#pragma unroll
    for (int qq = 0; qq < 8; ++qq)
      q[qq][tid] = qc[((size_t)b * L_ + q0 + qq) * DM_ + h * 64 + tid];
  }
  __syncthreads();
  for (int k = tid; k < L_; k += 256) {
    const float* krow = kvc + ((size_t)b * L_ + k) * 1024 + h * 64;
    float kr[64];
#pragma unroll
    for (int d = 0; d < 64; ++d) kr[d] = krow[d];
#pragma unroll
    for (int qq = 0; qq < 8; ++qq) {
      float dot = 0.f;
#pragma unroll
      for (int d = 0; d < 64; ++d) dot += q[qq][d] * kr[d];
      sc[qq][k] = dot * 0.125f;
    }
  }
  __syncthreads();
  // row-parallel softmax: 8 rows x 32 threads
  int sub = tid >> 5, sl = tid & 31;
  float lm = -INFINITY;
  for (int k = sl; k < L_; k += 32) lm = fmaxf(lm, sc[sub][k]);
  for (int off = 16; off; off >>= 1) lm = fmaxf(lm, __shfl_xor(lm, off, 32));
  float ls = 0.f;
  for (int k = sl; k < L_; k += 32) { float e = expf(sc[sub][k] - lm); sc[sub][k] = e; ls += e; }
  for (int off = 16; off; off >>= 1) ls += __shfl_xor(ls, off, 32);
  if (sl == 0) invs[sub] = 1.f / ls;
  __syncthreads();
  // PV
  int lane = tid % 64, grp = tid / 64;
  float acc[8] = {};
  for (int k = grp; k < L_; k += 4) {
    float v = kvc[((size_t)b * L_ + k) * 1024 + 512 + h * 64 + lane];
#pragma unroll
    for (int qq = 0; qq < 8; ++qq) acc[qq] += sc[qq][k] * v;
  }
#pragma unroll
  for (int qq = 0; qq < 8; ++qq) pv[grp][qq][lane] = acc[qq];
  __syncthreads();
  for (int o = tid; o < 512; o += 256) {
    int qq = o / 64, d = o % 64;
    float s = (pv[0][qq][d] + pv[1][qq][d] + pv[2][qq][d] + pv[3][qq][d]) * invs[qq];
    ctx[((size_t)b * L_ + q0 + qq) * DM_ + h * 64 + d] = s;
  }
}

// ---------------- host-side helpers -----------------------------------------
static inline void gemm(hipStream_t s, const float* A, const float* Bm, const float* bias,
                        const float* res, float* C, int M, int N, int K, int res_mod, int act) {
  dim3 grid((N + 63) / 64, (M + 63) / 64);
  gemm_f32<<<grid, 256, 0, s>>>(A, Bm, bias, res, C, M, N, K, res_mod, act);
}

static inline void prob_attention(hipStream_t s, const float* qkv, const int* sidx,
                                  float* MME, int* TOP, float* CTT, float* VME, float* CTX) {
  probM<<<B_ * H_ * L_ / 4, 256, 0, s>>>(qkv, sidx, MME);
  topk40<<<B_ * H_, 256, 0, s>>>(MME, TOP);
  prob_ctx_top<<<B_ * H_ * SK_, 256, 0, s>>>(qkv, TOP, CTT);
  vmean_k<<<B_ * H_, 256, 0, s>>>(qkv, VME);
  fill_ctx<<<ML_ * DM_ / 256, 256, 0, s>>>(VME, CTX);
  scatter_ctx<<<B_ * H_ * SK_ * DH_ / 256, 256, 0, s>>>(CTT, TOP, CTX);
}

extern "C" void kernel_launch(void* const* d_in, const int* in_sizes, int n_in,
                              void* d_out, int out_size, void* d_ws, size_t ws_size,
                              hipStream_t stream) {
  const float* inflow   = (const float*)d_in[4];
  const float* W_emb_e  = (const float*)d_in[5];
  const float* b_emb_e  = (const float*)d_in[6];
  const float* W_emb_d  = (const float*)d_in[7];
  const float* b_emb_d  = (const float*)d_in[8];
  const float* enc_Wqkv = (const float*)d_in[9];
  const float* enc_bqkv = (const float*)d_in[10];
  const float* enc_Wo   = (const float*)d_in[11];
  const float* enc_bo   = (const float*)d_in[12];
  const float* enc_ln1g = (const float*)d_in[13];
  const float* enc_ln1b = (const float*)d_in[14];
  const float* enc_Wf1  = (const float*)d_in[15];
  const float* enc_bf1  = (const float*)d_in[16];
  const float* enc_Wf2  = (const float*)d_in[17];
  const float* enc_bf2  = (const float*)d_in[18];
  const float* enc_ln2g = (const float*)d_in[19];
  const float* enc_ln2b = (const float*)d_in[20];
  const float* enc_ng   = (const float*)d_in[21];
  const float* enc_nb   = (const float*)d_in[22];
  const float* dec_Wqkv = (const float*)d_in[23];
  const float* dec_bqkv = (const float*)d_in[24];
  const float* dec_Wo_s = (const float*)d_in[25];
  const float* dec_bo_s = (const float*)d_in[26];
  const float* dec_ln1g = (const float*)d_in[27];
  const float* dec_ln1b = (const float*)d_in[28];
  const float* dec_Wq_c = (const float*)d_in[29];
  const float* dec_bq_c = (const float*)d_in[30];
  const float* dec_Wkv  = (const float*)d_in[31];
  const float* dec_bkv  = (const float*)d_in[32];
  const float* dec_Wo_c = (const float*)d_in[33];
  const float* dec_bo_c = (const float*)d_in[34];
  const float* dec_ln2g = (const float*)d_in[35];
  const float* dec_ln2b = (const float*)d_in[36];
  const float* dec_Wf1  = (const float*)d_in[37];
  const float* dec_bf1  = (const float*)d_in[38];
  const float* dec_Wf2  = (const float*)d_in[39];
  const float* dec_bf2  = (const float*)d_in[40];
  const float* dec_ln3g = (const float*)d_in[41];
  const float* dec_ln3b = (const float*)d_in[42];
  const float* W_proj   = (const float*)d_in[43];
  const float* b_proj   = (const float*)d_in[44];
  const float* W1       = (const float*)d_in[45];
  const float* b1       = (const float*)d_in[46];
  const float* W3       = (const float*)d_in[47];
  const float* b3       = (const float*)d_in[48];
  const int*   samp     = (const int*)d_in[49];
  float* out = (float*)d_out;

  float* ws = (float*)d_ws;
  float* PE  = ws; ws += L_ * DM_;
  float* X   = ws; ws += ML_ * 12;
  float* ENC = ws; ws += ML_ * DM_;
  float* DEC = ws; ws += ML_ * DM_;
  float* BIG = ws; ws += ML_ * DFF_;      // qkv / (qc,kvc) / ffn-hidden overlay
  float* CTX = ws; ws += ML_ * DM_;
  float* MME = ws; ws += B_ * H_ * L_;
  float* CTT = ws; ws += B_ * H_ * SK_ * DH_;
  float* VME = ws; ws += B_ * H_ * DH_;
  int*   TOP = (int*)ws; ws += B_ * H_ * SK_;
  float* H1  = ws; ws += ML_ * 128;
  float* O12 = ws; ws += ML_ * 12;

  pe_kernel<<<(L_ * DM_ + 255) / 256, 256, 0, stream>>>(PE);
  extract_x<<<(ML_ * 12 + 255) / 256, 256, 0, stream>>>(inflow, X);

  // encoder embed: ENC = X @ W_emb_e + b + PE(row = m % L)
  gemm(stream, X, W_emb_e, b_emb_e, PE, ENC, ML_, DM_, 12, L_, 0);

  for (int i = 0; i < 2; ++i) {
    gemm(stream, ENC, enc_Wqkv + (size_t)i * DM_ * 3 * DM_, enc_bqkv + i * 3 * DM_,
         nullptr, BIG, ML_, 3 * DM_, DM_, ML_, 0);
    prob_attention(stream, BIG, samp + (size_t)i * L_ * SK_, MME, TOP, CTT, VME, CTX);
    gemm(stream, CTX, enc_Wo + (size_t)i * DM_ * DM_, enc_bo + i * DM_,
         ENC, ENC, ML_, DM_, DM_, ML_, 0);
    layernorm_ip<<<ML_, 256, 0, stream>>>(ENC, enc_ln1g + i * DM_, enc_ln1b + i * DM_);
    gemm(stream, ENC, enc_Wf1 + (size_t)i * DM_ * DFF_, enc_bf1 + i * DFF_,
         nullptr, BIG, ML_, DFF_, DM_, ML_, 1);
    gemm(stream, BIG, enc_Wf2 + (size_t)i * DFF_ * DM_, enc_bf2 + i * DM_,
         ENC, ENC, ML_, DM_, DFF_, ML_, 0);
    layernorm_ip<<<ML_, 256, 0, stream>>>(ENC, enc_ln2g + i * DM_, enc_ln2b + i * DM_);
  }
  layernorm_ip<<<ML_, 256, 0, stream>>>(ENC, enc_ng, enc_nb);

  // decoder embed + self (prob) attention
  gemm(stream, X, W_emb_d, b_emb_d, PE, DEC, ML_, DM_, 12, L_, 0);
  gemm(stream, DEC, dec_Wqkv, dec_bqkv, nullptr, BIG, ML_, 3 * DM_, DM_, ML_, 0);
  prob_attention(stream, BIG, samp + (size_t)2 * L_ * SK_, MME, TOP, CTT, VME, CTX);
  gemm(stream, CTX, dec_Wo_s, dec_bo_s, DEC, DEC, ML_, DM_, DM_, ML_, 0);
  layernorm_ip<<<ML_, 256, 0, stream>>>(DEC, dec_ln1g, dec_ln1b);

  // cross attention
  float* QC = BIG;
  float* KVC = BIG + (size_t)ML_ * DM_;
  gemm(stream, DEC, dec_Wq_c, dec_bq_c, nullptr, QC, ML_, DM_, DM_, ML_, 0);
  gemm(stream, ENC, dec_Wkv, dec_bkv, nullptr, KVC, ML_, 2 * DM_, DM_, ML_, 0);
  cross_attn<<<B_ * H_ * (L_ / 8), 256, 0, stream>>>(QC, KVC, CTX);
  gemm(stream, CTX, dec_Wo_c, dec_bo_c, DEC, DEC, ML_, DM_, DM_, ML_, 0);
  layernorm_ip<<<ML_, 256, 0, stream>>>(DEC, dec_ln2g, dec_ln2b);

  // decoder FFN
  gemm(stream, DEC, dec_Wf1, dec_bf1, nullptr, BIG, ML_, DFF_, DM_, ML_, 1);
  gemm(stream, BIG, dec_Wf2, dec_bf2, DEC, DEC, ML_, DM_, DFF_, ML_, 0);
  layernorm_ip<<<ML_, 256, 0, stream>>>(DEC, dec_ln3g, dec_ln3b);

  // head: O12 = DEC@W_proj + b + X ; H1 = relu(O12@W1 + b1) ; out = H1@W3 + b3
  gemm(stream, DEC, W_proj, b_proj, X, O12, ML_, 12, DM_, ML_, 0);
  gemm(stream, O12, W1, b1, nullptr, H1, ML_, 128, 12, ML_, 2);
  gemm(stream, H1, W3, b3, nullptr, out, ML_, 3, 128, ML_, 0);
}

// Round 2
// 1666.142 us; speedup vs baseline: 4.1267x; 4.1267x over previous
//
#include <hip/hip_runtime.h>
#include <math.h>

#define B_ 4
#define H_ 8
#define L_ 1520
#define DM_ 512
#define DFF_ 2048
#define SK_ 40
#define ML_ (B_*L_)   /* 6080 rows */
#define MP_ 6144      /* padded rows for MFMA GEMM */

typedef unsigned short u16;
typedef short s8v __attribute__((ext_vector_type(8)));
typedef float f4 __attribute__((ext_vector_type(4)));

__device__ __forceinline__ u16 f2b(float x) {
  union { float f; unsigned u; } c; c.f = x;
  unsigned r = c.u + 0x7FFFu + ((c.u >> 16) & 1u);
  return (u16)(r >> 16);
}
__device__ __forceinline__ float b2f(u16 h) {
  union { unsigned u; float f; } c; c.u = ((unsigned)h) << 16;
  return c.f;
}
__device__ __forceinline__ float gelu_tanh(float x) {
  float x3 = x * x * x;
  return 0.5f * x * (1.f + tanhf(0.79788456080286536f * (x + 0.044715f * x3)));
}

// ---------------- positional encoding (double precision to match numpy) ----
__global__ __launch_bounds__(256) void pe_kernel(float* __restrict__ pe) {
  int idx = blockIdx.x * 256 + threadIdx.x;
  if (idx >= L_ * DM_) return;
  int pos = idx / DM_, i = idx % DM_;
  double expo = (double)(2 * (i / 2)) / (double)DM_;
  double ang = (double)pos / pow(10000.0, expo);
  pe[idx] = (i & 1) ? (float)cos(ang) : (float)sin(ang);
}

// ---------------- x = inflow[:,2:14].reshape (contiguous slice) -------------
__global__ __launch_bounds__(256) void extract_x(const float* __restrict__ inflow,
                                                 float* __restrict__ X) {
  int idx = blockIdx.x * 256 + threadIdx.x;
  if (idx >= ML_ * 12) return;
  int b = idx / (L_ * 12);
  int rem = idx - b * (L_ * 12);
  X[idx] = inflow[(size_t)b * 14 * L_ + 2 * L_ + rem];
}

// ---------------- weight convert + transpose: W[K][N] -> bf16 Wt[N][K] ------
__global__ __launch_bounds__(256) void cvt_wt(const float* __restrict__ W,
                                              u16* __restrict__ Wt, int K, int N) {
  int idx = blockIdx.x * 256 + threadIdx.x;   // grid exact: N*K/256
  int n = idx / K, k = idx % K;
  Wt[idx] = f2b(W[(size_t)k * N + n]);
}

// ---------------- activation fp32[6080][512] -> bf16[6144][512], pad 0 ------
__global__ __launch_bounds__(256) void cvt_act(const float* __restrict__ Xf,
                                               u16* __restrict__ Xb) {
  int idx = blockIdx.x * 256 + threadIdx.x;   // grid exact: MP_*512/256
  int row = idx >> 9;
  Xb[idx] = (row < ML_) ? f2b(Xf[idx]) : 0;
}

// ---------------- generic fp32 GEMM (small shapes only) ---------------------
__global__ __launch_bounds__(256) void gemm_f32(
    const float* __restrict__ A, const float* __restrict__ Bm,
    const float* __restrict__ bias, const float* __restrict__ res,
    float* __restrict__ C, int M, int N, int K, int res_mod, int act) {
  __shared__ float As[16][65];
  __shared__ float Bs[16][64];
  int bm = blockIdx.y * 64, bn = blockIdx.x * 64;
  int tid = threadIdx.x;
  int tx = tid % 16, ty = tid / 16;
  float acc[4][4] = {};
  for (int k0 = 0; k0 < K; k0 += 16) {
#pragma unroll
    for (int i = 0; i < 4; ++i) {
      int idx = tid + i * 256;
      int r = idx / 16, c = idx % 16;
      int gm = bm + r, gk = k0 + c;
      As[c][r] = (gm < M && gk < K) ? A[(size_t)gm * K + gk] : 0.f;
    }
#pragma unroll
    for (int i = 0; i < 4; ++i) {
      int idx = tid + i * 256;
      int r = idx / 64, c = idx % 64;
      int gk = k0 + r, gn = bn + c;
      Bs[r][c] = (gk < K && gn < N) ? Bm[(size_t)gk * N + gn] : 0.f;
    }
    __syncthreads();
#pragma unroll
    for (int kk = 0; kk < 16; ++kk) {
      float a[4], b[4];
#pragma unroll
      for (int i = 0; i < 4; ++i) a[i] = As[kk][ty + 16 * i];
#pragma unroll
      for (int j = 0; j < 4; ++j) b[j] = Bs[kk][tx + 16 * j];
#pragma unroll
      for (int i = 0; i < 4; ++i)
#pragma unroll
        for (int j = 0; j < 4; ++j) acc[i][j] += a[i] * b[j];
    }
    __syncthreads();
  }
#pragma unroll
  for (int i = 0; i < 4; ++i) {
    int gm = bm + ty + 16 * i;
    if (gm >= M) continue;
#pragma unroll
    for (int j = 0; j < 4; ++j) {
      int gn = bn + tx + 16 * j;
      if (gn >= N) continue;
      float v = acc[i][j];
      if (bias) v += bias[gn];
      if (res) v += res[(size_t)(gm % res_mod) * N + gn];
      if (act == 1) v = gelu_tanh(v);
      else if (act == 2) v = fmaxf(v, 0.f);
      C[(size_t)gm * N + gn] = v;
    }
  }
}

// ---------------- bf16 MFMA GEMM: C = act(A@Bt^T + bias [+ res]) ------------
// A [MP_][K] bf16, Bt [N][K] bf16 (pre-transposed weight), K%32==0, N%128==0.
__global__ __launch_bounds__(256) void gemm_bf16(
    const u16* __restrict__ A, const u16* __restrict__ Bt,
    const float* __restrict__ bias, const float* __restrict__ res,
    float* __restrict__ Cf, u16* __restrict__ Cb,
    int N, int K, int act) {
  __shared__ __align__(16) u16 As[128 * 40];
  __shared__ __align__(16) u16 Bs[128 * 40];
  const int t = threadIdx.x, w = t >> 6, lane = t & 63;
  const int lg = lane >> 4, li = lane & 15;
  const int bm = blockIdx.y * 128, bn = blockIdx.x * 128;
  const int wr = (w >> 1) * 64, wc = (w & 1) * 64;
  f4 acc[4][4];
#pragma unroll
  for (int i = 0; i < 4; ++i)
#pragma unroll
    for (int j = 0; j < 4; ++j) acc[i][j] = f4{0.f, 0.f, 0.f, 0.f};
  const int srow = t >> 2, scol = (t & 3) * 8;
  for (int k0 = 0; k0 < K; k0 += 32) {
    s8v a0 = *(const s8v*)(A + (size_t)(bm + srow) * K + k0 + scol);
    s8v a1 = *(const s8v*)(A + (size_t)(bm + 64 + srow) * K + k0 + scol);
    s8v b0 = *(const s8v*)(Bt + (size_t)(bn + srow) * K + k0 + scol);
    s8v b1 = *(const s8v*)(Bt + (size_t)(bn + 64 + srow) * K + k0 + scol);
    *(s8v*)(As + srow * 40 + scol) = a0;
    *(s8v*)(As + (64 + srow) * 40 + scol) = a1;
    *(s8v*)(Bs + srow * 40 + scol) = b0;
    *(s8v*)(Bs + (64 + srow) * 40 + scol) = b1;
    __syncthreads();
    s8v af[4], bf[4];
#pragma unroll
    for (int f = 0; f < 4; ++f) {
      af[f] = *(const s8v*)(As + (wr + f * 16 + li) * 40 + lg * 8);
      bf[f] = *(const s8v*)(Bs + (wc + f * 16 + li) * 40 + lg * 8);
    }
#pragma unroll
    for (int fi = 0; fi < 4; ++fi)
#pragma unroll
      for (int fj = 0; fj < 4; ++fj)
        acc[fi][fj] = __builtin_amdgcn_mfma_f32_16x16x32_bf16(af[fi], bf[fj], acc[fi][fj], 0, 0, 0);
    __syncthreads();
  }
#pragma unroll
  for (int fi = 0; fi < 4; ++fi)
#pragma unroll
    for (int fj = 0; fj < 4; ++fj)
#pragma unroll
      for (int r = 0; r < 4; ++r) {
        int row = bm + wr + fi * 16 + lg * 4 + r;
        int col = bn + wc + fj * 16 + li;
        float v = acc[fi][fj][r] + bias[col];
        if (res && row < ML_) v += res[(size_t)row * N + col];
        if (act == 1) v = gelu_tanh(v);
        if (Cf && row < ML_) Cf[(size_t)row * N + col] = v;
        if (Cb) Cb[(size_t)row * N + col] = f2b(v);
      }
}

// ---------------- layernorm (in-place fp32 + bf16 out) ----------------------
__global__ __launch_bounds__(256) void layernorm_ip(float* __restrict__ Xb,
                                                    const float* __restrict__ g,
                                                    const float* __restrict__ bta,
                                                    u16* __restrict__ outb) {
  int row = blockIdx.x;
  float* x = Xb + (size_t)row * DM_;
  int tid = threadIdx.x;
  float v0 = x[tid], v1 = x[tid + 256];
  __shared__ float red[256];
  red[tid] = v0 + v1;
  __syncthreads();
  for (int s = 128; s; s >>= 1) { if (tid < s) red[tid] += red[tid + s]; __syncthreads(); }
  float mu = red[0] / (float)DM_;
  __syncthreads();
  float d0 = v0 - mu, d1 = v1 - mu;
  red[tid] = d0 * d0 + d1 * d1;
  __syncthreads();
  for (int s = 128; s; s >>= 1) { if (tid < s) red[tid] += red[tid + s]; __syncthreads(); }
  float rs = rsqrtf(red[0] / (float)DM_ + 1e-5f);
  float r0 = d0 * rs * g[tid] + bta[tid];
  float r1 = d1 * rs * g[tid + 256] + bta[tid + 256];
  x[tid] = r0; x[tid + 256] = r1;
  outb[(size_t)row * DM_ + tid] = f2b(r0);
  outb[(size_t)row * DM_ + tid + 256] = f2b(r1);
}

// ---------------- ProbSparse sparsity measure M (bf16 qkv) ------------------
__global__ __launch_bounds__(256) void probM(const u16* __restrict__ qkv,
                                             const int* __restrict__ sidx,
                                             float* __restrict__ Mout) {
  int wid = threadIdx.x / 64, lane = threadIdx.x % 64;
  int g = blockIdx.x * 4 + wid;
  int l = g % L_;
  int bh = g / L_;
  int h = bh % H_, b = bh / H_;
  __shared__ float qs[4][64];
  qs[wid][lane] = b2f(qkv[((size_t)b * L_ + l) * 1536 + h * 64 + lane]);
  __syncthreads();
  float dot = 0.f;
  if (lane < SK_) {
    int ks = sidx[l * SK_ + lane];
    const u16* kr = qkv + ((size_t)b * L_ + ks) * 1536 + 512 + h * 64;
#pragma unroll
    for (int j = 0; j < 8; ++j) {
      s8v v = *(const s8v*)(kr + j * 8);
#pragma unroll
      for (int i = 0; i < 8; ++i) dot += qs[wid][j * 8 + i] * b2f((u16)v[i]);
    }
  }
  float vmax = (lane < SK_) ? dot : -INFINITY;
  float vsum = (lane < SK_) ? dot : 0.f;
  for (int off = 32; off; off >>= 1) {
    vmax = fmaxf(vmax, __shfl_xor(vmax, off));
    vsum += __shfl_xor(vsum, off);
  }
  if (lane == 0) Mout[g] = vmax - vsum / (float)L_;
}

// ---------------- top-40 per (b,h), tie-break smaller index -----------------
__global__ __launch_bounds__(256) void topk40(const float* __restrict__ Mv,
                                              int* __restrict__ top) {
  int bh = blockIdx.x;
  __shared__ float vals[L_];
  __shared__ float rbv[256];
  __shared__ int rbi[256];
  const float* m = Mv + (size_t)bh * L_;
  for (int i = threadIdx.x; i < L_; i += 256) vals[i] = m[i];
  __syncthreads();
  for (int it = 0; it < SK_; ++it) {
    float bv = -INFINITY;
    int bi = -1;
    for (int i = threadIdx.x; i < L_; i += 256) {
      float v = vals[i];
      if (v > bv || (v == bv && (unsigned)i < (unsigned)bi)) { bv = v; bi = i; }
    }
    rbv[threadIdx.x] = bv; rbi[threadIdx.x] = bi;
    __syncthreads();
    for (int s = 128; s; s >>= 1) {
      if (threadIdx.x < s) {
        float ov = rbv[threadIdx.x + s]; int oi = rbi[threadIdx.x + s];
        if (ov > rbv[threadIdx.x] ||
            (ov == rbv[threadIdx.x] && (unsigned)oi < (unsigned)rbi[threadIdx.x])) {
          rbv[threadIdx.x] = ov; rbi[threadIdx.x] = oi;
        }
      }
      __syncthreads();
    }
    if (threadIdx.x == 0) { top[bh * SK_ + it] = rbi[0]; vals[rbi[0]] = -INFINITY; }
    __syncthreads();
  }
}

// ---------------- MFMA flash attention ---------------------------------------
// MODE 0: cross attention. Qm=QCb [MP_][512], KVm=KVCb [MP_][1024]; out ctxb.
// MODE 1: top-40 prob attention. Qm=KVm=QKVb [MP_][1536]; rows via top; out ctt.
template<int MODE>
__global__ __launch_bounds__(256) void flash_attn(
    const u16* __restrict__ Qm, const u16* __restrict__ KVm,
    const int* __restrict__ top, float* __restrict__ ctt,
    u16* __restrict__ ctxb) {
  constexpr int NQB = (MODE == 0) ? 24 : 1;
  constexpr int QSTR = (MODE == 0) ? 512 : 1536;
  constexpr int KSTR = (MODE == 0) ? 1024 : 1536;
  __shared__ __align__(16) u16 K_lds[64 * 72];
  __shared__ __align__(16) u16 Vt_lds[64 * 72];
  __shared__ __align__(16) u16 P_lds[4 * 16 * 72];
  const int bh = blockIdx.x / NQB, qb = blockIdx.x % NQB;
  const int h = bh & 7, b = bh >> 3;
  const int qoff = h * 64;
  const int koff = ((MODE == 0) ? 0 : 512) + h * 64;
  const int voff = ((MODE == 0) ? 512 : 1024) + h * 64;
  const int t = threadIdx.x, w = t >> 6, lane = t & 63;
  const int lg = lane >> 4, li = lane & 15;

  // Q fragments (held in registers for the whole kernel)
  int qrow;
  if (MODE == 0) {
    int q = qb * 64 + w * 16 + li;
    qrow = b * L_ + ((q < L_) ? q : (L_ - 1));
  } else {
    int u = w * 16 + li;
    qrow = b * L_ + top[bh * SK_ + ((u < SK_) ? u : (SK_ - 1))];
  }
  s8v qf0 = *(const s8v*)(Qm + (size_t)qrow * QSTR + qoff + lg * 8);
  s8v qf1 = *(const s8v*)(Qm + (size_t)qrow * QSTR + qoff + 32 + lg * 8);

  f4 o[4];
#pragma unroll
  for (int n = 0; n < 4; ++n) o[n] = f4{0.f, 0.f, 0.f, 0.f};
  float m_run[4] = {-INFINITY, -INFINITY, -INFINITY, -INFINITY};
  float l_run[4] = {0.f, 0.f, 0.f, 0.f};

  for (int kt = 0; kt < 24; ++kt) {
    const int kb = kt * 64;
    // stage K (row-major) and V (transposed) tiles
#pragma unroll
    for (int r = 0; r < 2; ++r) {
      int slot = r * 256 + t;
      int key = slot >> 3, d = (slot & 7) * 8;
      int kk = kb + key;
      int grow = b * L_ + ((kk < L_) ? kk : (L_ - 1));
      s8v kv = *(const s8v*)(KVm + (size_t)grow * KSTR + koff + d);
      *(s8v*)(K_lds + key * 72 + d) = kv;
      s8v vv = *(const s8v*)(KVm + (size_t)grow * KSTR + voff + d);
#pragma unroll
      for (int i = 0; i < 8; ++i) Vt_lds[(d + i) * 72 + key] = (u16)vv[i];
    }
    __syncthreads();
    // S = Q @ K^T / 8
    f4 s[4];
#pragma unroll
    for (int c = 0; c < 4; ++c) {
      s8v k0f = *(const s8v*)(K_lds + (c * 16 + li) * 72 + lg * 8);
      s8v k1f = *(const s8v*)(K_lds + (c * 16 + li) * 72 + 32 + lg * 8);
      f4 z = f4{0.f, 0.f, 0.f, 0.f};
      z = __builtin_amdgcn_mfma_f32_16x16x32_bf16(qf0, k0f, z, 0, 0, 0);
      z = __builtin_amdgcn_mfma_f32_16x16x32_bf16(qf1, k1f, z, 0, 0, 0);
      s[c] = z * 0.125f;
    }
    if (kt == 23) {
#pragma unroll
      for (int c = 0; c < 4; ++c) {
        int key = kb + c * 16 + li;
        if (key >= L_) { s[c][0] = -INFINITY; s[c][1] = -INFINITY; s[c][2] = -INFINITY; s[c][3] = -INFINITY; }
      }
    }
    // online softmax per q-row
    float p[4][4];
#pragma unroll
    for (int r = 0; r < 4; ++r) {
      float tm = fmaxf(fmaxf(s[0][r], s[1][r]), fmaxf(s[2][r], s[3][r]));
      tm = fmaxf(tm, __shfl_xor(tm, 1));
      tm = fmaxf(tm, __shfl_xor(tm, 2));
      tm = fmaxf(tm, __shfl_xor(tm, 4));
      tm = fmaxf(tm, __shfl_xor(tm, 8));
      float mn = fmaxf(m_run[r], tm);
      float sc = expf(m_run[r] - mn);
      float rs = 0.f;
#pragma unroll
      for (int c = 0; c < 4; ++c) { p[c][r] = expf(s[c][r] - mn); rs += p[c][r]; }
      rs += __shfl_xor(rs, 1);
      rs += __shfl_xor(rs, 2);
      rs += __shfl_xor(rs, 4);
      rs += __shfl_xor(rs, 8);
      l_run[r] = l_run[r] * sc + rs;
      m_run[r] = mn;
#pragma unroll
      for (int n = 0; n < 4; ++n) o[n][r] *= sc;
    }
    // write P (bf16) to per-wave LDS
#pragma unroll
    for (int c = 0; c < 4; ++c)
#pragma unroll
      for (int r = 0; r < 4; ++r)
        P_lds[w * 1152 + (lg * 4 + r) * 72 + c * 16 + li] = f2b(p[c][r]);
    __syncthreads();
    // O += P @ V
#pragma unroll
    for (int ks = 0; ks < 2; ++ks) {
      s8v pa = *(const s8v*)(P_lds + w * 1152 + li * 72 + ks * 32 + lg * 8);
#pragma unroll
      for (int n = 0; n < 4; ++n) {
        s8v vb = *(const s8v*)(Vt_lds + (n * 16 + li) * 72 + ks * 32 + lg * 8);
        o[n] = __builtin_amdgcn_mfma_f32_16x16x32_bf16(pa, vb, o[n], 0, 0, 0);
      }
    }
    __syncthreads();
  }
  // epilogue
#pragma unroll
  for (int n = 0; n < 4; ++n)
#pragma unroll
    for (int r = 0; r < 4; ++r) {
      float val = o[n][r] / l_run[r];
      int d = n * 16 + li;
      if (MODE == 0) {
        int q = qb * 64 + w * 16 + lg * 4 + r;
        if (q < L_) ctxb[((size_t)(b * L_ + q)) * DM_ + h * 64 + d] = f2b(val);
      } else {
        int u = w * 16 + lg * 4 + r;
        if (u < SK_) ctt[((size_t)(bh * SK_ + u)) * 64 + d] = val;
      }
    }
}

// ---------------- V mean over L per (b,h) -----------------------------------
__global__ __launch_bounds__(256) void vmean_k(const u16* __restrict__ qkv,
                                               float* __restrict__ vmean) {
  int bh = blockIdx.x;
  int h = bh % H_, b = bh / H_;
  int lane = threadIdx.x % 64, grp = threadIdx.x / 64;
  __shared__ float pv[4][64];
  float acc = 0.f;
  for (int k = grp; k < L_; k += 4)
    acc += b2f(qkv[((size_t)b * L_ + k) * 1536 + 1024 + h * 64 + lane]);
  pv[grp][lane] = acc;
  __syncthreads();
  if (threadIdx.x < 64)
    vmean[bh * 64 + threadIdx.x] =
        (pv[0][threadIdx.x] + pv[1][threadIdx.x] + pv[2][threadIdx.x] + pv[3][threadIdx.x]) / (float)L_;
}

// ---------------- ctx = broadcast vmean (bf16), then scatter top ------------
__global__ __launch_bounds__(256) void fill_ctx(const float* __restrict__ vmean,
                                                u16* __restrict__ ctxb) {
  int idx = blockIdx.x * 256 + threadIdx.x;   // grid exact: ML_*DM_/256
  int d = idx % 64;
  int h = (idx / 64) % H_;
  int b = idx / (L_ * DM_);
  ctxb[idx] = f2b(vmean[(b * H_ + h) * 64 + d]);
}

__global__ __launch_bounds__(256) void scatter_ctx(const float* __restrict__ ctt,
                                                   const int* __restrict__ top,
                                                   u16* __restrict__ ctxb) {
  int idx = blockIdx.x * 256 + threadIdx.x;   // grid exact: B*H*40*64/256
  int d = idx % 64;
  int u = (idx / 64) % SK_;
  int bh = idx / (64 * SK_);
  int h = bh % H_, b = bh / H_;
  int l = top[bh * SK_ + u];
  ctxb[((size_t)b * L_ + l) * DM_ + h * 64 + d] = f2b(ctt[idx]);
}

// ---------------- host side --------------------------------------------------
extern "C" void kernel_launch(void* const* d_in, const int* in_sizes, int n_in,
                              void* d_out, int out_size, void* d_ws, size_t ws_size,
                              hipStream_t stream) {
  const float* inflow   = (const float*)d_in[4];
  const float* W_emb_e  = (const float*)d_in[5];
  const float* b_emb_e  = (const float*)d_in[6];
  const float* W_emb_d  = (const float*)d_in[7];
  const float* b_emb_d  = (const float*)d_in[8];
  const float* enc_Wqkv = (const float*)d_in[9];
  const float* enc_bqkv = (const float*)d_in[10];
  const float* enc_Wo   = (const float*)d_in[11];
  const float* enc_bo   = (const float*)d_in[12];
  const float* enc_ln1g = (const float*)d_in[13];
  const float* enc_ln1b = (const float*)d_in[14];
  const float* enc_Wf1  = (const float*)d_in[15];
  const float* enc_bf1  = (const float*)d_in[16];
  const float* enc_Wf2  = (const float*)d_in[17];
  const float* enc_bf2  = (const float*)d_in[18];
  const float* enc_ln2g = (const float*)d_in[19];
  const float* enc_ln2b = (const float*)d_in[20];
  const float* enc_ng   = (const float*)d_in[21];
  const float* enc_nb   = (const float*)d_in[22];
  const float* dec_Wqkv = (const float*)d_in[23];
  const float* dec_bqkv = (const float*)d_in[24];
  const float* dec_Wo_s = (const float*)d_in[25];
  const float* dec_bo_s = (const float*)d_in[26];
  const float* dec_ln1g = (const float*)d_in[27];
  const float* dec_ln1b = (const float*)d_in[28];
  const float* dec_Wq_c = (const float*)d_in[29];
  const float* dec_bq_c = (const float*)d_in[30];
  const float* dec_Wkv  = (const float*)d_in[31];
  const float* dec_bkv  = (const float*)d_in[32];
  const float* dec_Wo_c = (const float*)d_in[33];
  const float* dec_bo_c = (const float*)d_in[34];
  const float* dec_ln2g = (const float*)d_in[35];
  const float* dec_ln2b = (const float*)d_in[36];
  const float* dec_Wf1  = (const float*)d_in[37];
  const float* dec_bf1  = (const float*)d_in[38];
  const float* dec_Wf2  = (const float*)d_in[39];
  const float* dec_bf2  = (const float*)d_in[40];
  const float* dec_ln3g = (const float*)d_in[41];
  const float* dec_ln3b = (const float*)d_in[42];
  const float* W_proj   = (const float*)d_in[43];
  const float* b_proj   = (const float*)d_in[44];
  const float* W1       = (const float*)d_in[45];
  const float* b1       = (const float*)d_in[46];
  const float* W3       = (const float*)d_in[47];
  const float* b3       = (const float*)d_in[48];
  const int*   samp     = (const int*)d_in[49];
  float* out = (float*)d_out;

  float* ws  = (float*)d_ws;
  float* PE  = ws;                       // 1520*512 = 778240
  float* X   = PE + 778240;              // 72960
  float* ACT = X + 72960;                // 3112960 (ENC, later DEC overlay)
  float* REG = ACT + 3112960;            // 6291456 shared region
  float* MME = REG + 6291456;            // 48640
  float* CTT = MME + 48640;              // 81920
  float* VME = CTT + 81920;              // 2048
  int*   TOP = (int*)(VME + 2048);       // 1280 ints
  float* TAIL = VME + 2048 + 1280;
  u16* ENCb = (u16*)TAIL;                       // 6144*512
  u16* DECb = (u16*)(TAIL + 1572864);
  u16* CTXb = (u16*)(TAIL + 2 * 1572864);
  u16* WBF  = (u16*)(TAIL + 3 * 1572864);       // 10485760 bf16

  // region overlays
  u16* QKVb = (u16*)REG;                 // [6144][1536]
  u16* FFb  = (u16*)REG;                 // [6144][2048]
  u16* QCb  = (u16*)REG;                 // [6144][512]
  u16* KVCb = (u16*)REG + 3145728;       // [6144][1024]
  float* O12 = REG;                      // [6080][12]
  float* H1  = REG + 72960;              // [6080][128]

  // weight slots (bf16, transposed [N][K])
  u16* Wt_qkv_e0 = WBF + 0;
  u16* Wt_qkv_e1 = WBF + 786432;
  u16* Wt_o_e0   = WBF + 1572864;
  u16* Wt_o_e1   = WBF + 1835008;
  u16* Wt_f1_e0  = WBF + 2097152;
  u16* Wt_f1_e1  = WBF + 3145728;
  u16* Wt_f2_e0  = WBF + 4194304;
  u16* Wt_f2_e1  = WBF + 5242880;
  u16* Wt_qkv_d  = WBF + 6291456;
  u16* Wt_o_s    = WBF + 7077888;
  u16* Wt_q_c    = WBF + 7340032;
  u16* Wt_kv_c   = WBF + 7602176;
  u16* Wt_o_c    = WBF + 8126464;
  u16* Wt_f1_d   = WBF + 8388608;
  u16* Wt_f2_d   = WBF + 9437184;

  auto CW = [&](const float* src, u16* dst, int K, int N) {
    cvt_wt<<<(N * K) / 256, 256, 0, stream>>>(src, dst, K, N);
  };
  auto GB = [&](const u16* A, const u16* Bt, const float* bias, const float* res,
                float* Cf, u16* Cb, int N, int K, int act) {
    dim3 g(N / 128, MP_ / 128);
    gemm_bf16<<<g, 256, 0, stream>>>(A, Bt, bias, res, Cf, Cb, N, K, act);
  };
  auto GF = [&](const float* A, const float* Bm, const float* bias, const float* res,
                float* C, int M, int N, int K, int res_mod, int act) {
    dim3 g((N + 63) / 64, (M + 63) / 64);
    gemm_f32<<<g, 256, 0, stream>>>(A, Bm, bias, res, C, M, N, K, res_mod, act);
  };
  auto PROB = [&](const int* sidx) {
    probM<<<B_ * H_ * L_ / 4, 256, 0, stream>>>(QKVb, sidx, MME);
    topk40<<<B_ * H_, 256, 0, stream>>>(MME, TOP);
    flash_attn<1><<<B_ * H_, 256, 0, stream>>>(QKVb, QKVb, TOP, CTT, nullptr);
    vmean_k<<<B_ * H_, 256, 0, stream>>>(QKVb, VME);
    fill_ctx<<<ML_ * DM_ / 256, 256, 0, stream>>>(VME, CTXb);
    scatter_ctx<<<B_ * H_ * SK_ * 64 / 256, 256, 0, stream>>>(CTT, TOP, CTXb);
  };

  pe_kernel<<<(L_ * DM_ + 255) / 256, 256, 0, stream>>>(PE);
  extract_x<<<(ML_ * 12 + 255) / 256, 256, 0, stream>>>(inflow, X);

  // weight conversions
  CW(enc_Wqkv,                 Wt_qkv_e0, 512, 1536);
  CW(enc_Wqkv + 512 * 1536,    Wt_qkv_e1, 512, 1536);
  CW(enc_Wo,                   Wt_o_e0,   512, 512);
  CW(enc_Wo + 512 * 512,       Wt_o_e1,   512, 512);
  CW(enc_Wf1,                  Wt_f1_e0,  512, 2048);
  CW(enc_Wf1 + 512 * 2048,     Wt_f1_e1,  512, 2048);
  CW(enc_Wf2,                  Wt_f2_e0,  2048, 512);
  CW(enc_Wf2 + 2048 * 512,     Wt_f2_e1,  2048, 512);
  CW(dec_Wqkv,                 Wt_qkv_d,  512, 1536);
  CW(dec_Wo_s,                 Wt_o_s,    512, 512);
  CW(dec_Wq_c,                 Wt_q_c,    512, 512);
  CW(dec_Wkv,                  Wt_kv_c,   512, 1024);
  CW(dec_Wo_c,                 Wt_o_c,    512, 512);
  CW(dec_Wf1,                  Wt_f1_d,   512, 2048);
  CW(dec_Wf2,                  Wt_f2_d,   2048, 512);

  // ---------------- encoder ----------------
  GF(X, W_emb_e, b_emb_e, PE, ACT, ML_, DM_, 12, L_, 0);
  cvt_act<<<MP_ * DM_ / 256, 256, 0, stream>>>(ACT, ENCb);

  const u16* Wqkv_e[2] = {Wt_qkv_e0, Wt_qkv_e1};
  const u16* Wo_e[2]   = {Wt_o_e0, Wt_o_e1};
  const u16* Wf1_e[2]  = {Wt_f1_e0, Wt_f1_e1};
  const u16* Wf2_e[2]  = {Wt_f2_e0, Wt_f2_e1};
  for (int i = 0; i < 2; ++i) {
    GB(ENCb, Wqkv_e[i], enc_bqkv + i * 1536, nullptr, nullptr, QKVb, 1536, 512, 0);
    PROB(samp + (size_t)i * L_ * SK_);
    GB(CTXb, Wo_e[i], enc_bo + i * 512, ACT, ACT, nullptr, 512, 512, 0);
    layernorm_ip<<<ML_, 256, 0, stream>>>(ACT, enc_ln1g + i * 512, enc_ln1b + i * 512, ENCb);
    GB(ENCb, Wf1_e[i], enc_bf1 + i * 2048, nullptr, nullptr, FFb, 2048, 512, 1);
    GB(FFb, Wf2_e[i], enc_bf2 + i * 512, ACT, ACT, nullptr, 512, 2048, 0);
    layernorm_ip<<<ML_, 256, 0, stream>>>(ACT, enc_ln2g + i * 512, enc_ln2b + i * 512, ENCb);
  }
  layernorm_ip<<<ML_, 256, 0, stream>>>(ACT, enc_ng, enc_nb, ENCb);

  // ---------------- decoder ----------------
  GF(X, W_emb_d, b_emb_d, PE, ACT, ML_, DM_, 12, L_, 0);   // DEC overlays ENC fp32
  cvt_act<<<MP_ * DM_ / 256, 256, 0, stream>>>(ACT, DECb);
  GB(DECb, Wt_qkv_d, dec_bqkv, nullptr, nullptr, QKVb, 1536, 512, 0);
  PROB(samp + (size_t)2 * L_ * SK_);
  GB(CTXb, Wt_o_s, dec_bo_s, ACT, ACT, nullptr, 512, 512, 0);
  layernorm_ip<<<ML_, 256, 0, stream>>>(ACT, dec_ln1g, dec_ln1b, DECb);

  // cross attention
  GB(DECb, Wt_q_c, dec_bq_c, nullptr, nullptr, QCb, 512, 512, 0);
  GB(ENCb, Wt_kv_c, dec_bkv, nullptr, nullptr, KVCb, 1024, 512, 0);
  flash_attn<0><<<B_ * H_ * 24, 256, 0, stream>>>(QCb, KVCb, nullptr, nullptr, CTXb);
  GB(CTXb, Wt_o_c, dec_bo_c, ACT, ACT, nullptr, 512, 512, 0);
  layernorm_ip<<<ML_, 256, 0, stream>>>(ACT, dec_ln2g, dec_ln2b, DECb);

  // decoder FFN
  GB(DECb, Wt_f1_d, dec_bf1, nullptr, nullptr, FFb, 2048, 512, 1);
  GB(FFb, Wt_f2_d, dec_bf2, ACT, ACT, nullptr, 512, 2048, 0);
  layernorm_ip<<<ML_, 256, 0, stream>>>(ACT, dec_ln3g, dec_ln3b, DECb);

  // head (fp32, tiny)
  GF(ACT, W_proj, b_proj, X, O12, ML_, 12, DM_, ML_, 0);
  GF(O12, W1, b1, nullptr, H1, ML_, 128, 12, ML_, 2);
  GF(H1, W3, b3, nullptr, out, ML_, 3, 128, ML_, 0);
}